// Round 2
// baseline (40.711 us; speedup 1.0000x reference)
//
#include <hip/hip_runtime.h>

#define BB 16
#define DD 64
#define HH 128
#define WW 240
#define NS 10   // samples per level (SAMPLE_POINTS + 1)
#define NL 3    // pyramid levels
#define BLK 128 // 32 KiB LDS/block -> 5 blocks/CU = 10 waves/CU

typedef const __attribute__((address_space(1))) void gvoid_t;
typedef __attribute__((address_space(3))) void lvoid_t;

__global__ __launch_bounds__(BLK) void pcv_kernel(
    const float* __restrict__ cv,
    const int* __restrict__ radius_p,
    const float* __restrict__ disp_in,
    float* __restrict__ out)
{
    // d-major LDS: lane i always hits bank i%32 -> conflict-free random-d gather
    __shared__ float lds[DD * BLK];
    const int tid = threadIdx.x;
    const int p = blockIdx.x * BLK + tid;   // grid sized exactly: no bounds check needed
    const int w = p % WW;
    const int h = (p / WW) % HH;
    const int b = p / (WW * HH);

    const float disp = disp_in[p];          // issue early, overlaps staging

    const float r = (float)(*radius_p);
    // match Python: interval = (2.0 * radius) / sample_nums (double), weak-cast to f32
    const float interval = (float)((2.0 * (double)r) / 9.0);

    // stage full disparity column via direct global->LDS DMA (no VGPR round trip).
    // LDS dest is wave-uniform: d*BLK + (tid & ~63); HW adds lane*4 -> lands at [d][tid].
    const float* col = cv + ((size_t)b * DD) * (HH * WW) + (size_t)h * WW + w;
    const int wave_base = tid & ~63;
    #pragma unroll
    for (int d = 0; d < DD; ++d) {
        __builtin_amdgcn_global_load_lds(
            (gvoid_t*)(col + (size_t)d * (HH * WW)),
            (lvoid_t*)&lds[d * BLK + wave_base],
            4, 0, 0);
    }
    // dependency is wave-internal (each thread reads its own wave's rows):
    // one vmcnt drain, no __syncthreads needed.
    asm volatile("s_waitcnt vmcnt(0)" ::: "memory");

    float* outp = out + ((size_t)b * (NL * NS)) * (HH * WW) + (size_t)h * WW + w;

    float rd = disp;
    int Dl = DD;
    #pragma unroll
    for (int lvl = 0; lvl < NL; ++lvl) {
        const float lower = rd - r;
        const float dmax = (float)(Dl - 1);
        #pragma unroll
        for (int s = 0; s < NS; ++s) {
            float cand = lower + (float)s * interval;
            float cc = fminf(fmaxf(ceilf(cand),  0.0f), dmax);
            float fc = fminf(fmaxf(floorf(cand), 0.0f), dmax);
            float fr = cc - cand;      // floor_rate (post-clip, as in reference)
            float cr = 1.0f - fr;      // ceil_rate
            int ic = (int)cc;
            int fi = (int)fc;
            float vc, vf;
            if (lvl == 0) {
                vc = lds[ic * BLK + tid];
                vf = lds[fi * BLK + tid];
            } else if (lvl == 1) {
                vc = 0.5f * (lds[(2 * ic) * BLK + tid] + lds[(2 * ic + 1) * BLK + tid]);
                vf = 0.5f * (lds[(2 * fi) * BLK + tid] + lds[(2 * fi + 1) * BLK + tid]);
            } else {
                float c0 = 0.5f * (lds[(4 * ic) * BLK + tid] + lds[(4 * ic + 1) * BLK + tid]);
                float c1 = 0.5f * (lds[(4 * ic + 2) * BLK + tid] + lds[(4 * ic + 3) * BLK + tid]);
                float f0 = 0.5f * (lds[(4 * fi) * BLK + tid] + lds[(4 * fi + 1) * BLK + tid]);
                float f1 = 0.5f * (lds[(4 * fi + 2) * BLK + tid] + lds[(4 * fi + 3) * BLK + tid]);
                vc = 0.5f * (c0 + c1);   // matches mean-of-means rounding
                vf = 0.5f * (f0 + f1);
            }
            outp[(size_t)(lvl * NS + s) * (HH * WW)] = vc * cr + vf * fr;
        }
        rd *= 0.5f;   // exact: ref_disp = cur_disp / 2^lvl
        Dl >>= 1;
    }
}

extern "C" void kernel_launch(void* const* d_in, const int* in_sizes, int n_in,
                              void* d_out, int out_size, void* d_ws, size_t ws_size,
                              hipStream_t stream) {
    const float* cv     = (const float*)d_in[0];
    const int*   radius = (const int*)  d_in[1];
    const float* disp   = (const float*)d_in[2];
    float*       out    = (float*)d_out;

    const int npix = BB * HH * WW;          // 491520, divisible by 128
    pcv_kernel<<<dim3(npix / BLK), dim3(BLK), 0, stream>>>(cv, radius, disp, out);
}

// Round 3
// 36.585 us; speedup vs baseline: 1.1128x; 1.1128x over previous
//
#include <hip/hip_runtime.h>

#define BB 16
#define DD 64
#define HH 128
#define WW 240
#define HW (HH * WW)   // 30720, divisible by BLK -> block never crosses b
#define NS 10          // samples per level (SAMPLE_POINTS + 1)
#define NL 3           // pyramid levels
#define BLK 256

__global__ __launch_bounds__(BLK) void pcv_kernel(
    const float* __restrict__ cv,
    const int* __restrict__ radius_p,
    const float* __restrict__ disp_in,
    float* __restrict__ out)
{
    // d-major LDS: lane i always hits bank i%32 -> conflict-free random-d gather
    __shared__ float lds[DD * BLK];
    const int tid = threadIdx.x;
    const int p = blockIdx.x * BLK + tid;
    const int b = p / HW;                   // uniform across block (HW % BLK == 0)
    const int pix = p - b * HW;             // flat h*W+w, contiguous across block

    const float disp = disp_in[p];          // issue early, overlaps staging

    const float r = (float)(*radius_p);
    // match Python: interval = (2.0 * radius) / sample_nums (double), weak-cast to f32
    const float interval = (float)((2.0 * (double)r) / 9.0);

    // Vectorized staging: each d-row of this block's tile is a contiguous
    // 1 KiB segment. 16 iters x (global_load_dwordx4 + ds_write_b128).
    {
        const int pixbase = blockIdx.x * BLK - b * HW;   // block-uniform
        const float* src = cv + (size_t)b * DD * HW + pixbase;
        const int q = tid & 63;             // float4 slot within a d-row
        const int dbase = tid >> 6;         // wave id: rows dbase, dbase+4, ...
        #pragma unroll
        for (int it = 0; it < 16; ++it) {
            const int d = it * 4 + dbase;
            float4 v = *reinterpret_cast<const float4*>(src + (size_t)d * HW + q * 4);
            *reinterpret_cast<float4*>(&lds[d * BLK + q * 4]) = v;
        }
    }
    __syncthreads();   // rows staged by other waves

    float* outp = out + (size_t)b * (NL * NS) * HW + pix;

    float rd = disp;
    int Dl = DD;
    #pragma unroll
    for (int lvl = 0; lvl < NL; ++lvl) {
        const float lower = rd - r;
        const float dmax = (float)(Dl - 1);
        #pragma unroll
        for (int s = 0; s < NS; ++s) {
            float cand = lower + (float)s * interval;
            float cc = fminf(fmaxf(ceilf(cand),  0.0f), dmax);
            float fc = fminf(fmaxf(floorf(cand), 0.0f), dmax);
            float fr = cc - cand;      // floor_rate (post-clip, as in reference)
            float cr = 1.0f - fr;      // ceil_rate
            int ic = (int)cc;
            int fi = (int)fc;
            float vc, vf;
            if (lvl == 0) {
                vc = lds[ic * BLK + tid];
                vf = lds[fi * BLK + tid];
            } else if (lvl == 1) {
                vc = 0.5f * (lds[(2 * ic) * BLK + tid] + lds[(2 * ic + 1) * BLK + tid]);
                vf = 0.5f * (lds[(2 * fi) * BLK + tid] + lds[(2 * fi + 1) * BLK + tid]);
            } else {
                float c0 = 0.5f * (lds[(4 * ic) * BLK + tid] + lds[(4 * ic + 1) * BLK + tid]);
                float c1 = 0.5f * (lds[(4 * ic + 2) * BLK + tid] + lds[(4 * ic + 3) * BLK + tid]);
                float f0 = 0.5f * (lds[(4 * fi) * BLK + tid] + lds[(4 * fi + 1) * BLK + tid]);
                float f1 = 0.5f * (lds[(4 * fi + 2) * BLK + tid] + lds[(4 * fi + 3) * BLK + tid]);
                vc = 0.5f * (c0 + c1);   // matches mean-of-means rounding
                vf = 0.5f * (f0 + f1);
            }
            outp[(size_t)(lvl * NS + s) * HW] = vc * cr + vf * fr;
        }
        rd *= 0.5f;   // exact: ref_disp = cur_disp / 2^lvl
        Dl >>= 1;
    }
}

extern "C" void kernel_launch(void* const* d_in, const int* in_sizes, int n_in,
                              void* d_out, int out_size, void* d_ws, size_t ws_size,
                              hipStream_t stream) {
    const float* cv     = (const float*)d_in[0];
    const int*   radius = (const int*)  d_in[1];
    const float* disp   = (const float*)d_in[2];
    float*       out    = (float*)d_out;

    const int npix = BB * HH * WW;          // 491520, divisible by 256
    pcv_kernel<<<dim3(npix / BLK), dim3(BLK), 0, stream>>>(cv, radius, disp, out);
}

// Round 4
// 34.650 us; speedup vs baseline: 1.1749x; 1.0558x over previous
//
#include <hip/hip_runtime.h>
#include <hip/hip_fp16.h>

#define BB 16
#define DD 64
#define HH 128
#define WW 240
#define HW (HH * WW)   // 30720, divisible by BLK -> block never crosses b
#define NS 10          // samples per level (SAMPLE_POINTS + 1)
#define NL 3           // pyramid levels
#define BLK 256
#define NWORD (DD / 2) // 32 packed d-pair words per pixel

__device__ inline unsigned pack2h(float lo, float hi) {
    __half2 h = __floats2half2_rn(lo, hi);
    return *reinterpret_cast<unsigned*>(&h);
}
__device__ inline float2 unpack2h(unsigned u) {
    __half2 h = *reinterpret_cast<__half2*>(&u);
    return __half22float2(h);
}
// extract half `sel` (0=lo,1=hi) of packed word as float
__device__ inline float exth(unsigned u, int sel) {
    unsigned short us = (unsigned short)(u >> (sel << 4));
    __half_raw hr; hr.x = us;
    return __half2float(*reinterpret_cast<__half*>(&hr));
}

__global__ __launch_bounds__(BLK, 4) void pcv_kernel(
    const float* __restrict__ cv,
    const int* __restrict__ radius_p,
    const float* __restrict__ disp_in,
    float* __restrict__ out)
{
    // packed d-pair words, word-major: lane i always hits bank i%32 -> conflict-free
    __shared__ unsigned ldsw[NWORD * BLK];   // 32 KiB -> 4 blocks/CU (VGPR-capped)
    const int tid = threadIdx.x;
    const int p = blockIdx.x * BLK + tid;
    const int b = p / HW;                    // uniform across block (HW % BLK == 0)
    const int pix = p - b * HW;

    const float disp = disp_in[p];           // issue early, overlaps staging

    const float r = (float)(*radius_p);
    // match Python: interval = (2.0*radius)/sample_nums (double), weak-cast to f32
    const float interval = (float)((2.0 * (double)r) / 9.0);

    // Staging: per iter load rows 2j and 2j+1 (contiguous 1 KiB segments),
    // pack to f16 pairs, one ds_write_b128 (4 pixels x 1 word-row).
    {
        const int pixbase = blockIdx.x * BLK - b * HW;   // block-uniform
        const float* src = cv + (size_t)b * DD * HW + pixbase;
        const int q = tid & 63;              // float4 slot within a row
        const int jbase = tid >> 6;          // wave id 0..3
        #pragma unroll
        for (int it = 0; it < 8; ++it) {
            const int j = it * 4 + jbase;    // word row 0..31
            float4 v0 = *reinterpret_cast<const float4*>(src + (size_t)(2 * j)     * HW + q * 4);
            float4 v1 = *reinterpret_cast<const float4*>(src + (size_t)(2 * j + 1) * HW + q * 4);
            uint4 wv;
            wv.x = pack2h(v0.x, v1.x);
            wv.y = pack2h(v0.y, v1.y);
            wv.z = pack2h(v0.z, v1.z);
            wv.w = pack2h(v0.w, v1.w);
            *reinterpret_cast<uint4*>(&ldsw[j * BLK + q * 4]) = wv;
        }
    }
    __syncthreads();

    float* outp = out + (size_t)b * (NL * NS) * HW + pix;

    float rd = disp;
    int Dl = DD;
    #pragma unroll
    for (int lvl = 0; lvl < NL; ++lvl) {
        const float lower = rd - r;
        const float dmax = (float)(Dl - 1);
        #pragma unroll
        for (int s = 0; s < NS; ++s) {
            float cand = lower + (float)s * interval;
            float cc = fminf(fmaxf(ceilf(cand),  0.0f), dmax);
            float fc = fminf(fmaxf(floorf(cand), 0.0f), dmax);
            float fr = cc - cand;      // floor_rate (post-clip, as in reference)
            float cr = 1.0f - fr;      // ceil_rate
            int ic = (int)cc;
            int fi = (int)fc;
            float vc, vf;
            if (lvl == 0) {
                unsigned uf = ldsw[(fi >> 1) * BLK + tid];
                unsigned uc = ldsw[(ic >> 1) * BLK + tid];
                vf = exth(uf, fi & 1);
                vc = exth(uc, ic & 1);
            } else if (lvl == 1) {
                float2 a = unpack2h(ldsw[fi * BLK + tid]);
                float2 c = unpack2h(ldsw[ic * BLK + tid]);
                vf = 0.5f * (a.x + a.y);
                vc = 0.5f * (c.x + c.y);
            } else {
                float2 a0 = unpack2h(ldsw[(2 * fi)     * BLK + tid]);
                float2 a1 = unpack2h(ldsw[(2 * fi + 1) * BLK + tid]);
                float2 c0 = unpack2h(ldsw[(2 * ic)     * BLK + tid]);
                float2 c1 = unpack2h(ldsw[(2 * ic + 1) * BLK + tid]);
                vf = 0.5f * (0.5f * (a0.x + a0.y) + 0.5f * (a1.x + a1.y));
                vc = 0.5f * (0.5f * (c0.x + c0.y) + 0.5f * (c1.x + c1.y));
            }
            outp[(size_t)(lvl * NS + s) * HW] = vc * cr + vf * fr;
        }
        rd *= 0.5f;   // exact: ref_disp = cur_disp / 2^lvl
        Dl >>= 1;
    }
}

extern "C" void kernel_launch(void* const* d_in, const int* in_sizes, int n_in,
                              void* d_out, int out_size, void* d_ws, size_t ws_size,
                              hipStream_t stream) {
    const float* cv     = (const float*)d_in[0];
    const int*   radius = (const int*)  d_in[1];
    const float* disp   = (const float*)d_in[2];
    float*       out    = (float*)d_out;

    const int npix = BB * HH * WW;          // 491520, divisible by 256
    pcv_kernel<<<dim3(npix / BLK), dim3(BLK), 0, stream>>>(cv, radius, disp, out);
}